// Round 11
// baseline (212.000 us; speedup 1.0000x reference)
//
#include <hip/hip_runtime.h>

typedef unsigned short u16;
typedef unsigned int u32;

#define CH 128      // IN_CH == HEADS*HEAD_DIM == 128
#define NHEAD 4
#define NEG_SLOPE 0.2f
#define ROWS_PER_BLOCK 32   // x-tile rows per block
#define XPAD 132            // xs row stride (fp32): breaks 16-way column-read conflicts

#define LOG_NPB 5
#define NPB 32              // nodes per coarse bucket (bucket = dst >> 5)
#define NBMAX 1600          // LDS bound on bucket count (N <= 51200)
#define BCAP 1536           // records per bucket (E[edges]=1024, ~16 sigma)
#define KMB 3               // BCAP / 512 records per thread in binBagg
#define GPAD 16             // bucket-cursor padding (one per 64B line)
#define BINA_BLOCKS 256     // gcur atomics = BINA_BLOCKS * NB ~ 400k over 1563 lines

typedef __attribute__((ext_vector_type(8))) short bf16x8;   // 8 bf16 (4 VGPRs)
typedef __attribute__((ext_vector_type(4))) float f32x4;    // MFMA C/D

static __device__ __forceinline__ float bitf(u32 i) {
    float f; __builtin_memcpy(&f, &i, 4); return f;
}
static __device__ __forceinline__ float bflo(u32 v) { return bitf(v << 16); }
static __device__ __forceinline__ float bfhi(u32 v) { return bitf(v & 0xffff0000u); }
static __device__ __forceinline__ u16 f2bf(float f) {
    u32 i; __builtin_memcpy(&i, &f, 4);
    return (u16)((i + 0x7fffu + ((i >> 16) & 1u)) >> 16);   // RNE
}
static __device__ __forceinline__ float lrelu(float v) { return v > 0.f ? v : NEG_SLOPE * v; }

// edge_index accessor: mode32 ? int32 layout : int64 layout (low word)
static __device__ __forceinline__ int ei_at(const int* __restrict__ ei, int mode32, size_t idx) {
    return mode32 ? ei[idx] : ei[2 * idx];
}

// ---------------- k0: init — zero gcur + build SWIZZLED bf16 W fragments ----------------
// Wsw[(nt*4+ks)*64 + lane] (uint4 = 8 bf16) holds the B-fragment for
// mfma_f32_16x16x32_bf16: elem j <-> W[ks*32 + (lane>>4)*4 + (j&3) + 16*(j>>2)]
//                                    [nt*16 + (lane&15)]
__global__ __launch_bounds__(256) void init_kernel(
    const float* __restrict__ W, uint4* __restrict__ Wsw, int* __restrict__ gcur, int nGcur)
{
    const int t = blockIdx.x * 256 + threadIdx.x;    // grid 16x256 = 4096
    if (t < 2048) {
        const int lane = t & 63, ks = (t >> 6) & 3, nt = t >> 8;
        const int col = nt * 16 + (lane & 15);
        const int kb = ks * 32 + ((lane >> 4) << 2);
        u16 v[8];
#pragma unroll
        for (int j = 0; j < 8; ++j) {
            int kk = kb + (j & 3) + ((j >> 2) << 4);
            v[j] = f2bf(W[(size_t)kk * CH + col]);
        }
        uint4 q;
        q.x = (u32)v[0] | ((u32)v[1] << 16);
        q.y = (u32)v[2] | ((u32)v[3] << 16);
        q.z = (u32)v[4] | ((u32)v[5] << 16);
        q.w = (u32)v[6] | ((u32)v[7] << 16);
        Wsw[t] = q;
    }
    for (int i = t; i < nGcur; i += 4096) gcur[i] = 0;
}

// ======== k1: blocks [0,BINA_BLOCKS) do binA, rest do MFMA GEMM ========
// GEMM h = x@W + logits via double-bf16 MFMA (r10-proven, absmax-verified).
// binA's hist arrays (3*NBMAX ints = 19.2 KB) overlay the 32 KB Wb buffer.
__global__ __launch_bounds__(256) void gemmbin_kernel(
    const float* __restrict__ x, const uint4* __restrict__ Wsw,
    const float* __restrict__ att_src, const float* __restrict__ att_dst,
    u16* __restrict__ h, float* __restrict__ asrc, float* __restrict__ adst, int N,
    const int* __restrict__ ei, int* __restrict__ gcur, u32* __restrict__ rec,
    int E, int NB)
{
    __shared__ float xs[ROWS_PER_BLOCK][XPAD];   // 16.9 KB (overlay: h-tile)
    __shared__ uint4 Wb[2048];                   // 32 KB (overlay: binA hist)

    const int tid = threadIdx.x;

    if (blockIdx.x < BINA_BLOCKS) {
        // ---- binA: partition edges into coarse buckets ----
        int* hist  = (int*)&Wb[0];             // 3 * NBMAX ints = 19.2 KB <= 32 KB
        int* hbase = hist + NBMAX;
        int* hcur  = hbase + NBMAX;
        const int mode32 = __syncthreads_or(ei[2 * tid + 1] != 0);
        for (int b = tid; b < NB; b += 256) { hist[b] = 0; hcur[b] = 0; }
        __syncthreads();
        const int chunk = (E + BINA_BLOCKS - 1) / BINA_BLOCKS;
        const int beg0 = blockIdx.x * chunk;
        const int end0 = min(E, beg0 + chunk);
#pragma unroll 4
        for (int e = beg0 + tid; e < end0; e += 256) {
            int dj = ei_at(ei, mode32, (size_t)E + e);
            atomicAdd(&hist[dj >> LOG_NPB], 1);
        }
        __syncthreads();
        for (int b = tid; b < NB; b += 256) {
            int c = hist[b];
            hbase[b] = c ? atomicAdd(&gcur[b * GPAD], c) : 0;
        }
        __syncthreads();
#pragma unroll 4
        for (int e = beg0 + tid; e < end0; e += 256) {
            int dj = ei_at(ei, mode32, (size_t)E + e);
            int sj = ei_at(ei, mode32, (size_t)e);
            int bkt = dj >> LOG_NPB;
            int r = atomicAdd(&hcur[bkt], 1);
            int pos = hbase[bkt] + r;
            if (pos < BCAP)
                rec[(size_t)bkt * BCAP + pos] = ((u32)sj << LOG_NPB) | (u32)(dj & (NPB - 1));
        }
        return;
    }

    // ---- stage ----
    const int gb = blockIdx.x - BINA_BLOCKS;
    const int r0b = gb * ROWS_PER_BLOCK;
#pragma unroll
    for (int i = 0; i < 8; ++i) Wb[tid + i * 256] = Wsw[tid + i * 256];
#pragma unroll
    for (int i = 0; i < 4; ++i) {
        int f = tid + i * 256;
        int row = f >> 5;
        int col = (f & 31) * 4;
        if (r0b + row < N)
            *(float4*)&xs[row][col] = *(const float4*)(x + (size_t)(r0b + row) * CH + col);
    }
    __syncthreads();

    const int lane = tid & 63;
    const int w = tid >> 6;
    const int g = lane >> 4;          // k-group
    const int a15 = lane & 15;
    const int rt = w & 1;             // row tile
    const int cb4 = w >> 1;           // col base / 64

    f32x4 acc[4] = {};                // acc[ct]: D[rt*16 + 4g+i][cb4*64 + ct*16 + a15]

#pragma unroll
    for (int ks = 0; ks < 4; ++ks) {
        const float* xr = &xs[rt * 16 + a15][ks * 32 + g * 4];
        float4 av0 = *(const float4*)xr;          // k = ks*32 + 4g + 0..3
        float4 av1 = *(const float4*)(xr + 16);   // k = ks*32 + 16 + 4g + 0..3
        float av[8] = {av0.x, av0.y, av0.z, av0.w, av1.x, av1.y, av1.z, av1.w};
        bf16x8 ahi, alo;
#pragma unroll
        for (int j = 0; j < 8; ++j) {
            u16 hb = f2bf(av[j]);
            ahi[j] = (short)hb;
            alo[j] = (short)f2bf(av[j] - bflo(hb));
        }
#pragma unroll
        for (int ct = 0; ct < 4; ++ct) {
            bf16x8 b = *(const bf16x8*)&Wb[((cb4 * 4 + ct) * 4 + ks) * 64 + lane];
            acc[ct] = __builtin_amdgcn_mfma_f32_16x16x32_bf16(alo, b, acc[ct], 0, 0, 0);
            acc[ct] = __builtin_amdgcn_mfma_f32_16x16x32_bf16(ahi, b, acc[ct], 0, 0, 0);
        }
    }

    // ---- logits from fp32 acc: head hb0 = 2*cb4 (ct 0,1), hb0+1 (ct 2,3) ----
    float as_c[4], ad_c[4];
#pragma unroll
    for (int ct = 0; ct < 4; ++ct) {
        int c = cb4 * 64 + ct * 16 + a15;
        as_c[ct] = att_src[c];
        ad_c[ct] = att_dst[c];
    }
#pragma unroll
    for (int i = 0; i < 4; ++i) {
        float s0 = acc[0][i] * as_c[0] + acc[1][i] * as_c[1];
        float s1 = acc[2][i] * as_c[2] + acc[3][i] * as_c[3];
        float d0 = acc[0][i] * ad_c[0] + acc[1][i] * ad_c[1];
        float d1 = acc[2][i] * ad_c[2] + acc[3][i] * ad_c[3];
#pragma unroll
        for (int o = 1; o < 16; o <<= 1) {      // reduce over a15 (16-lane groups)
            s0 += __shfl_xor(s0, o, 64);
            s1 += __shfl_xor(s1, o, 64);
            d0 += __shfl_xor(d0, o, 64);
            d1 += __shfl_xor(d1, o, 64);
        }
        if (a15 == 0) {
            int row = r0b + rt * 16 + g * 4 + i;
            if (row < N) {
                int hb0 = cb4 * 2;
                asrc[row * NHEAD + hb0]     = s0;
                asrc[row * NHEAD + hb0 + 1] = s1;
                adst[row * NHEAD + hb0]     = d0;
                adst[row * NHEAD + hb0 + 1] = d1;
            }
        }
    }

    // ---- h store: D -> LDS bf16 tile (overlay xs) -> coalesced u32 global ----
    __syncthreads();                   // all waves done reading xs
    u16* ht = (u16*)&xs[0][0];         // [32][128] bf16 tile, 8 KB
#pragma unroll
    for (int ct = 0; ct < 4; ++ct)
#pragma unroll
        for (int i = 0; i < 4; ++i)
            ht[(rt * 16 + g * 4 + i) * CH + cb4 * 64 + ct * 16 + a15] = f2bf(acc[ct][i]);
    __syncthreads();
    {
        const u32* ht32 = (const u32*)&xs[0][0];
        const int rw = w * 8;
#pragma unroll
        for (int r = 0; r < 8; ++r) {
            int row = r0b + rw + r;
            if (row < N)
                *(u32*)(h + (size_t)row * CH + lane * 2) = ht32[(rw + r) * 64 + lane];
        }
    }
}

// ======== k2: fused binB + aggregate — one block per 32-node bucket, 512 threads ========
// NPB=32 -> 1563 blocks (~6/CU queue, 4 resident = full wave cap) fixes r8/r10's
// 1.53-block/CU tail (52% occupancy). Phase 1 reads only this bucket's records.
__global__ __launch_bounds__(512) void binBagg_kernel(
    const u16* __restrict__ h, const float* __restrict__ asrc, const float* __restrict__ adst,
    const int* __restrict__ gcur, const u32* __restrict__ rec,
    const float* __restrict__ bias, float* __restrict__ out, int N)
{
    __shared__ int outb[BCAP + 32];   // 6.2 KB (+pad for prefetch overread)
    __shared__ int lcnt[NPB];
    __shared__ int lsc[NPB];
    __shared__ int lcur[NPB];
    const int tid = threadIdx.x;
    const int bkt = blockIdx.x;
    int cnt0 = gcur[bkt * GPAD];
    cnt0 = cnt0 < BCAP ? cnt0 : BCAP;
    const size_t rbase = (size_t)bkt * BCAP;

    if (tid < NPB) { lcnt[tid] = 0; lcur[tid] = 0; }

    u32 rc[KMB];
#pragma unroll
    for (int k = 0; k < KMB; ++k) {
        int i = tid + k * 512;
        rc[k] = (i < cnt0) ? rec[rbase + i] : 0xffffffffu;   // sj<<5|d < 1.7M, sentinel safe
    }
    __syncthreads();
#pragma unroll
    for (int k = 0; k < KMB; ++k)
        if (rc[k] != 0xffffffffu) atomicAdd(&lcnt[rc[k] & (NPB - 1)], 1);
    __syncthreads();
    if (tid < NPB) lsc[tid] = lcnt[tid];
    __syncthreads();
    for (int o = 1; o < NPB; o <<= 1) {
        int v = (tid < NPB && tid >= o) ? lsc[tid - o] : 0;
        __syncthreads();
        if (tid < NPB) lsc[tid] += v;
        __syncthreads();
    }
#pragma unroll
    for (int k = 0; k < KMB; ++k) {
        if (rc[k] != 0xffffffffu) {
            int local = rc[k] & (NPB - 1);
            int r = atomicAdd(&lcur[local], 1);
            int slot = (lsc[local] - lcnt[local]) + r;
            outb[slot] = (int)(rc[k] >> LOG_NPB);
        }
    }
    __syncthreads();

    // ---- agg phase: wave w handles locals w*4 .. w*4+3 (no barriers below) ----
    const int lane = tid & 63;
    const int wave = tid >> 6;        // 0..7
    const int g = lane >> 4;
    const int l = lane & 15;
    const int c8 = l * 8;
    const int head = l >> 2;

    for (int nl = 0; nl < 4; ++nl) {
        const int local = wave * 4 + nl;
        const int node = (bkt << LOG_NPB) + local;
        if (node >= N) continue;
        const int beg = lsc[local] - lcnt[local];
        const int end = lsc[local];
        const float4 ad4 = *(const float4*)(adst + node * 4);
        const float adh = (head == 0) ? ad4.x : (head == 1) ? ad4.y : (head == 2) ? ad4.z : ad4.w;
        const float4 asl = *(const float4*)(asrc + node * 4);
        const float aslh = (head == 0) ? asl.x : (head == 1) ? asl.y : (head == 2) ? asl.z : asl.w;
        const float mh = lrelu(aslh + adh);   // self-loop logit as softmax shift

        float acc[8];
#pragma unroll
        for (int k = 0; k < 8; ++k) acc[k] = 0.f;
        float s = 0.f;

        int e = beg + g;
        if (e < end) {
            uint4 hC[4]; float aC[4];
#pragma unroll
            for (int i = 0; i < 4; ++i) {              // prologue batch: e+0,4,8,12
                int ei = e + 4 * i;
                int j = outb[ei];                      // LDS, padded-safe
                j = ((u32)j < (u32)N) ? j : 0;
                float a = asrc[j * NHEAD + head];
                aC[i] = (ei < end) ? a : -1e30f;
                hC[i] = *(const uint4*)(h + (size_t)j * CH + c8);
            }
            for (;;) {
                const int ebase = e + 16;
                uint4 hP[4]; float aP[4];
#pragma unroll
                for (int i = 0; i < 4; ++i) {          // prefetch next batch
                    int ei = ebase + 4 * i;
                    int j = outb[ei];
                    j = ((u32)j < (u32)N) ? j : 0;
                    float a = asrc[j * NHEAD + head];
                    aP[i] = (ei < end) ? a : -1e30f;
                    hP[i] = *(const uint4*)(h + (size_t)j * CH + c8);
                }
#pragma unroll
                for (int i = 0; i < 4; ++i) {          // compute current batch
                    float w = __expf(lrelu(aC[i] + adh) - mh);   // a=-1e30 -> w=0
                    s += w;
                    acc[0] = fmaf(w, bflo(hC[i].x), acc[0]);
                    acc[1] = fmaf(w, bfhi(hC[i].x), acc[1]);
                    acc[2] = fmaf(w, bflo(hC[i].y), acc[2]);
                    acc[3] = fmaf(w, bfhi(hC[i].y), acc[3]);
                    acc[4] = fmaf(w, bflo(hC[i].z), acc[4]);
                    acc[5] = fmaf(w, bfhi(hC[i].z), acc[5]);
                    acc[6] = fmaf(w, bflo(hC[i].w), acc[6]);
                    acc[7] = fmaf(w, bfhi(hC[i].w), acc[7]);
                }
#pragma unroll
                for (int i = 0; i < 4; ++i) { aC[i] = aP[i]; hC[i] = hP[i]; }
                e = ebase;
                if (e >= end) break;
            }
        }
        if (g == 0) {   // self-loop message: w = exp(mh - mh) = 1 exactly
            s += 1.0f;
            uint4 hv = *(const uint4*)(h + (size_t)node * CH + c8);
            acc[0] += bflo(hv.x);
            acc[1] += bfhi(hv.x);
            acc[2] += bflo(hv.y);
            acc[3] += bfhi(hv.y);
            acc[4] += bflo(hv.z);
            acc[5] += bfhi(hv.z);
            acc[6] += bflo(hv.w);
            acc[7] += bfhi(hv.w);
        }
#pragma unroll
        for (int o = 16; o < 64; o <<= 1) {
            s += __shfl_xor(s, o, 64);
#pragma unroll
            for (int k = 0; k < 8; ++k) acc[k] += __shfl_xor(acc[k], o, 64);
        }
        if (g == 0) {
            const float inv = 1.f / (s + 1e-16f);
            float o0[8];
#pragma unroll
            for (int k = 0; k < 8; ++k) {
                float v = acc[k] * inv + bias[c8 + k];
                o0[k] = v > 0.f ? v : __expf(v) - 1.f;   // ELU alpha=1
            }
            float4 lo = make_float4(o0[0], o0[1], o0[2], o0[3]);
            float4 hi = make_float4(o0[4], o0[5], o0[6], o0[7]);
            *(float4*)(out + (size_t)node * CH + c8) = lo;
            *(float4*)(out + (size_t)node * CH + c8 + 4) = hi;
        }
    }
}

extern "C" void kernel_launch(void* const* d_in, const int* in_sizes, int n_in,
                              void* d_out, int out_size, void* d_ws, size_t ws_size,
                              hipStream_t stream)
{
    const float* x       = (const float*)d_in[0];
    const int*   ei      = (const int*)d_in[1];
    const float* W       = (const float*)d_in[2];
    const float* att_src = (const float*)d_in[3];
    const float* att_dst = (const float*)d_in[4];
    const float* bias    = (const float*)d_in[5];
    float* out = (float*)d_out;
    const int N = in_sizes[0] / CH;
    const int E = in_sizes[1] / 2;
    const int NB = (N + NPB - 1) / NPB;   // coarse buckets (1563 for N=50000)

    char* p = (char*)d_ws;
    auto alloc = [&](size_t bytes) { char* r = p; p += (bytes + 255) & ~(size_t)255; return r; };
    u16*   h    = (u16*)alloc((size_t)N * CH * 2);             // 12.8 MB
    float* asrc = (float*)alloc((size_t)N * NHEAD * 4);        // 0.8 MB
    float* adst = (float*)alloc((size_t)N * NHEAD * 4);        // 0.8 MB
    int*   gcur = (int*)alloc((size_t)NB * GPAD * 4);          // 100 KB
    u32*   rec  = (u32*)alloc((size_t)NB * BCAP * 4);          // 9.6 MB
    uint4* Wsw  = (uint4*)alloc((size_t)2048 * 16);            // 32 KB swizzled bf16 W

    const int gemmBlocks = (N + ROWS_PER_BLOCK - 1) / ROWS_PER_BLOCK;
    init_kernel<<<16, 256, 0, stream>>>(W, Wsw, gcur, NB * GPAD);
    gemmbin_kernel<<<BINA_BLOCKS + gemmBlocks, 256, 0, stream>>>(
        x, Wsw, att_src, att_dst, h, asrc, adst, N, ei, gcur, rec, E, NB);
    binBagg_kernel<<<NB, 512, 0, stream>>>(h, asrc, adst, gcur, rec, bias, out, N);
}

// Round 12
// 190.819 us; speedup vs baseline: 1.1110x; 1.1110x over previous
//
#include <hip/hip_runtime.h>

typedef unsigned short u16;
typedef unsigned int u32;

#define CH 128      // IN_CH == HEADS*HEAD_DIM == 128
#define NHEAD 4
#define NEG_SLOPE 0.2f
#define ROWS_PER_BLOCK 32   // x-tile rows per block
#define XPAD 132            // xs row stride (fp32): breaks 16-way column-read conflicts

#define LOG_NPB 7
#define NPB 128             // nodes per coarse bucket (bucket = dst >> 7)
#define NBMAX 400           // LDS bound on bucket count (N <= 51200)
#define BCAP 6144           // records per bucket (E[edges]=4096, ~32 sigma)
#define KMAX 24             // BCAP / 256 records per thread in binB
#define GPAD 16             // bucket-cursor padding (one per 64B line)
#define BINA_BLOCKS 256     // gcur atomics = BINA_BLOCKS * NB ~ 100k

typedef __attribute__((ext_vector_type(8))) short bf16x8;   // 8 bf16 (4 VGPRs)
typedef __attribute__((ext_vector_type(4))) float f32x4;    // MFMA C/D

static __device__ __forceinline__ float bitf(u32 i) {
    float f; __builtin_memcpy(&f, &i, 4); return f;
}
static __device__ __forceinline__ float bflo(u32 v) { return bitf(v << 16); }
static __device__ __forceinline__ float bfhi(u32 v) { return bitf(v & 0xffff0000u); }
static __device__ __forceinline__ u16 f2bf(float f) {
    u32 i; __builtin_memcpy(&i, &f, 4);
    return (u16)((i + 0x7fffu + ((i >> 16) & 1u)) >> 16);   // RNE
}
static __device__ __forceinline__ float lrelu(float v) { return v > 0.f ? v : NEG_SLOPE * v; }

// edge_index accessor: mode32 ? int32 layout : int64 layout (low word)
static __device__ __forceinline__ int ei_at(const int* __restrict__ ei, int mode32, size_t idx) {
    return mode32 ? ei[idx] : ei[2 * idx];
}

// ---------------- k0: init — zero gcur + build SWIZZLED bf16 W fragments ----------------
// Wsw[(nt*4+ks)*64 + lane] (uint4 = 8 bf16) holds the B-fragment for
// mfma_f32_16x16x32_bf16: elem j <-> W[ks*32 + (lane>>4)*4 + (j&3) + 16*(j>>2)]
//                                    [nt*16 + (lane&15)]
__global__ __launch_bounds__(256) void init_kernel(
    const float* __restrict__ W, uint4* __restrict__ Wsw, int* __restrict__ gcur, int nGcur)
{
    const int t = blockIdx.x * 256 + threadIdx.x;    // grid 16x256 = 4096
    if (t < 2048) {
        const int lane = t & 63, ks = (t >> 6) & 3, nt = t >> 8;
        const int col = nt * 16 + (lane & 15);
        const int kb = ks * 32 + ((lane >> 4) << 2);
        u16 v[8];
#pragma unroll
        for (int j = 0; j < 8; ++j) {
            int kk = kb + (j & 3) + ((j >> 2) << 4);
            v[j] = f2bf(W[(size_t)kk * CH + col]);
        }
        uint4 q;
        q.x = (u32)v[0] | ((u32)v[1] << 16);
        q.y = (u32)v[2] | ((u32)v[3] << 16);
        q.z = (u32)v[4] | ((u32)v[5] << 16);
        q.w = (u32)v[6] | ((u32)v[7] << 16);
        Wsw[t] = q;
    }
    for (int i = t; i < nGcur; i += 4096) gcur[i] = 0;
}

// ======== k1: blocks [0,BINA_BLOCKS) do binA, rest do MFMA GEMM (r10-proven) ========
// GEMM h = x@W + logits via double-bf16 MFMA (absmax-verified r10).
// binA's hist arrays (3*400 ints = 4.8 KB) overlay xs.
__global__ __launch_bounds__(256) void gemmbin_kernel(
    const float* __restrict__ x, const uint4* __restrict__ Wsw,
    const float* __restrict__ att_src, const float* __restrict__ att_dst,
    u16* __restrict__ h, float* __restrict__ asrc, float* __restrict__ adst, int N,
    const int* __restrict__ ei, int* __restrict__ gcur, u32* __restrict__ rec,
    int E, int NB)
{
    __shared__ float xs[ROWS_PER_BLOCK][XPAD];   // 16.9 KB (overlay: binA hist / h-tile)
    __shared__ uint4 Wb[2048];                   // 32 KB swizzled bf16 W fragments

    const int tid = threadIdx.x;

    if (blockIdx.x < BINA_BLOCKS) {
        // ---- binA: partition edges into coarse buckets ----
        int* hist  = (int*)&xs[0][0];          // 3 * NBMAX ints = 4.8 KB <= 16.9 KB
        int* hbase = hist + NBMAX;
        int* hcur  = hbase + NBMAX;
        const int mode32 = __syncthreads_or(ei[2 * tid + 1] != 0);
        for (int b = tid; b < NB; b += 256) { hist[b] = 0; hcur[b] = 0; }
        __syncthreads();
        const int chunk = (E + BINA_BLOCKS - 1) / BINA_BLOCKS;
        const int beg0 = blockIdx.x * chunk;
        const int end0 = min(E, beg0 + chunk);
#pragma unroll 4
        for (int e = beg0 + tid; e < end0; e += 256) {
            int dj = ei_at(ei, mode32, (size_t)E + e);
            atomicAdd(&hist[dj >> LOG_NPB], 1);
        }
        __syncthreads();
        for (int b = tid; b < NB; b += 256) {
            int c = hist[b];
            hbase[b] = c ? atomicAdd(&gcur[b * GPAD], c) : 0;
        }
        __syncthreads();
#pragma unroll 4
        for (int e = beg0 + tid; e < end0; e += 256) {
            int dj = ei_at(ei, mode32, (size_t)E + e);
            int sj = ei_at(ei, mode32, (size_t)e);
            int bkt = dj >> LOG_NPB;
            int r = atomicAdd(&hcur[bkt], 1);
            int pos = hbase[bkt] + r;
            if (pos < BCAP)
                rec[(size_t)bkt * BCAP + pos] = ((u32)sj << LOG_NPB) | (u32)(dj & (NPB - 1));
        }
        return;
    }

    // ---- stage ----
    const int gb = blockIdx.x - BINA_BLOCKS;
    const int r0b = gb * ROWS_PER_BLOCK;
#pragma unroll
    for (int i = 0; i < 8; ++i) Wb[tid + i * 256] = Wsw[tid + i * 256];
#pragma unroll
    for (int i = 0; i < 4; ++i) {
        int f = tid + i * 256;
        int row = f >> 5;
        int col = (f & 31) * 4;
        if (r0b + row < N)
            *(float4*)&xs[row][col] = *(const float4*)(x + (size_t)(r0b + row) * CH + col);
    }
    __syncthreads();

    const int lane = tid & 63;
    const int w = tid >> 6;
    const int g = lane >> 4;          // k-group
    const int a15 = lane & 15;
    const int rt = w & 1;             // row tile
    const int cb4 = w >> 1;           // col base / 64

    f32x4 acc[4] = {};                // acc[ct]: D[rt*16 + 4g+i][cb4*64 + ct*16 + a15]

#pragma unroll
    for (int ks = 0; ks < 4; ++ks) {
        const float* xr = &xs[rt * 16 + a15][ks * 32 + g * 4];
        float4 av0 = *(const float4*)xr;          // k = ks*32 + 4g + 0..3
        float4 av1 = *(const float4*)(xr + 16);   // k = ks*32 + 16 + 4g + 0..3
        float av[8] = {av0.x, av0.y, av0.z, av0.w, av1.x, av1.y, av1.z, av1.w};
        bf16x8 ahi, alo;
#pragma unroll
        for (int j = 0; j < 8; ++j) {
            u16 hb = f2bf(av[j]);
            ahi[j] = (short)hb;
            alo[j] = (short)f2bf(av[j] - bflo(hb));
        }
#pragma unroll
        for (int ct = 0; ct < 4; ++ct) {
            bf16x8 b = *(const bf16x8*)&Wb[((cb4 * 4 + ct) * 4 + ks) * 64 + lane];
            acc[ct] = __builtin_amdgcn_mfma_f32_16x16x32_bf16(alo, b, acc[ct], 0, 0, 0);
            acc[ct] = __builtin_amdgcn_mfma_f32_16x16x32_bf16(ahi, b, acc[ct], 0, 0, 0);
        }
    }

    // ---- logits from fp32 acc: head hb0 = 2*cb4 (ct 0,1), hb0+1 (ct 2,3) ----
    float as_c[4], ad_c[4];
#pragma unroll
    for (int ct = 0; ct < 4; ++ct) {
        int c = cb4 * 64 + ct * 16 + a15;
        as_c[ct] = att_src[c];
        ad_c[ct] = att_dst[c];
    }
#pragma unroll
    for (int i = 0; i < 4; ++i) {
        float s0 = acc[0][i] * as_c[0] + acc[1][i] * as_c[1];
        float s1 = acc[2][i] * as_c[2] + acc[3][i] * as_c[3];
        float d0 = acc[0][i] * ad_c[0] + acc[1][i] * ad_c[1];
        float d1 = acc[2][i] * ad_c[2] + acc[3][i] * ad_c[3];
#pragma unroll
        for (int o = 1; o < 16; o <<= 1) {      // reduce over a15 (16-lane groups)
            s0 += __shfl_xor(s0, o, 64);
            s1 += __shfl_xor(s1, o, 64);
            d0 += __shfl_xor(d0, o, 64);
            d1 += __shfl_xor(d1, o, 64);
        }
        if (a15 == 0) {
            int row = r0b + rt * 16 + g * 4 + i;
            if (row < N) {
                int hb0 = cb4 * 2;
                asrc[row * NHEAD + hb0]     = s0;
                asrc[row * NHEAD + hb0 + 1] = s1;
                adst[row * NHEAD + hb0]     = d0;
                adst[row * NHEAD + hb0 + 1] = d1;
            }
        }
    }

    // ---- h store: D -> LDS bf16 tile (overlay xs) -> coalesced u32 global ----
    __syncthreads();                   // all waves done reading xs
    u16* ht = (u16*)&xs[0][0];         // [32][128] bf16 tile, 8 KB
#pragma unroll
    for (int ct = 0; ct < 4; ++ct)
#pragma unroll
        for (int i = 0; i < 4; ++i)
            ht[(rt * 16 + g * 4 + i) * CH + cb4 * 64 + ct * 16 + a15] = f2bf(acc[ct][i]);
    __syncthreads();
    {
        const u32* ht32 = (const u32*)&xs[0][0];
        const int rw = w * 8;
#pragma unroll
        for (int r = 0; r < 8; ++r) {
            int row = r0b + rw + r;
            if (row < N)
                *(u32*)(h + (size_t)row * CH + lane * 2) = ht32[(rw + r) * 64 + lane];
        }
    }
}

// ---------------- k2: binB — per-bucket CSR build (r2-proven, ~13us) ----------------
// Records held in registers (static indexing); permuted csr segment staged in
// LDS (random 4B writes hit LDS, not HBM), then dumped coalesced.
__global__ __launch_bounds__(256) void binB_kernel(
    const int* __restrict__ gcur, const u32* __restrict__ rec,
    int* __restrict__ csr, int* __restrict__ begA, int* __restrict__ degA, int N)
{
    __shared__ int outb[BCAP];      // 24 KB staged csr segment
    __shared__ int lcnt[NPB];
    __shared__ int lsc[NPB];
    __shared__ int lcur[NPB];
    const int tid = threadIdx.x;
    const int bkt = blockIdx.x;
    int cnt0 = gcur[bkt * GPAD];
    cnt0 = cnt0 < BCAP ? cnt0 : BCAP;
    const size_t rbase = (size_t)bkt * BCAP;

    if (tid < NPB) { lcnt[tid] = 0; lcur[tid] = 0; }

    u32 rc[KMAX];
#pragma unroll
    for (int k = 0; k < KMAX; ++k) {
        int i = tid + k * 256;
        rc[k] = (i < cnt0) ? rec[rbase + i] : 0xffffffffu;   // sj<<7|d < 6.5M, sentinel safe
    }
    __syncthreads();
#pragma unroll
    for (int k = 0; k < KMAX; ++k)
        if (rc[k] != 0xffffffffu) atomicAdd(&lcnt[rc[k] & (NPB - 1)], 1);
    __syncthreads();
    if (tid < NPB) lsc[tid] = lcnt[tid];
    __syncthreads();
    for (int o = 1; o < NPB; o <<= 1) {
        int v = (tid < NPB && tid >= o) ? lsc[tid - o] : 0;
        __syncthreads();
        if (tid < NPB) lsc[tid] += v;
        __syncthreads();
    }
#pragma unroll
    for (int k = 0; k < KMAX; ++k) {
        if (rc[k] != 0xffffffffu) {
            int local = rc[k] & (NPB - 1);
            int r = atomicAdd(&lcur[local], 1);
            int slot = (lsc[local] - lcnt[local]) + r;
            outb[slot] = (int)(rc[k] >> LOG_NPB);
        }
    }
    __syncthreads();
    for (int i = tid; i < cnt0; i += 256)       // coalesced dump
        csr[rbase + i] = outb[i];
    if (tid < NPB) {
        int node = (bkt << LOG_NPB) + tid;
        if (node < N) {
            begA[node] = (int)rbase + (lsc[tid] - lcnt[tid]);
            degA[node] = lcnt[tid];
        }
    }
}

// ---------------- k3: per-node softmax + aggregate (r5-proven, 63.4us) ----------------
// Softmax shift = self-loop logit (shift-invariance). 4 edges/group/iter,
// depth-2 prefetch = 32 edge-slots in flight per wave.
__global__ __launch_bounds__(256) void agg_kernel(
    const u16* __restrict__ h, const float* __restrict__ asrc, const float* __restrict__ adst,
    const int* __restrict__ begA, const int* __restrict__ degA, const int* __restrict__ csr,
    const float* __restrict__ bias, float* __restrict__ out, int N)
{
    const int lane = threadIdx.x & 63;
    const int wave = threadIdx.x >> 6;
    const int node = blockIdx.x * 4 + wave;
    if (node >= N) return;   // whole-wave exit; no __syncthreads in this kernel
    const int g = lane >> 4;
    const int l = lane & 15;
    const int c8 = l * 8;
    const int head = l >> 2;
    const int beg = begA[node];
    const int end = beg + degA[node];
    const float4 ad4 = *(const float4*)(adst + node * 4);
    const float adh = (head == 0) ? ad4.x : (head == 1) ? ad4.y : (head == 2) ? ad4.z : ad4.w;
    const float4 asl = *(const float4*)(asrc + node * 4);
    const float aslh = (head == 0) ? asl.x : (head == 1) ? asl.y : (head == 2) ? asl.z : asl.w;
    const float mh = lrelu(aslh + adh);   // self-loop logit as softmax shift

    float acc[8];
#pragma unroll
    for (int k = 0; k < 8; ++k) acc[k] = 0.f;
    float s = 0.f;

    int e = beg + g;
    if (e < end) {
        uint4 hC[4]; float aC[4];
#pragma unroll
        for (int i = 0; i < 4; ++i) {              // prologue batch: e+0,4,8,12
            int ei = e + 4 * i;
            int j = csr[ei];                       // padded-safe
            j = ((u32)j < (u32)N) ? j : 0;
            float a = asrc[j * NHEAD + head];
            aC[i] = (ei < end) ? a : -1e30f;
            hC[i] = *(const uint4*)(h + (size_t)j * CH + c8);
        }
        for (;;) {
            const int ebase = e + 16;
            uint4 hP[4]; float aP[4];
#pragma unroll
            for (int i = 0; i < 4; ++i) {          // prefetch next batch
                int ei = ebase + 4 * i;
                int j = csr[ei];                   // padded-safe
                j = ((u32)j < (u32)N) ? j : 0;
                float a = asrc[j * NHEAD + head];
                aP[i] = (ei < end) ? a : -1e30f;
                hP[i] = *(const uint4*)(h + (size_t)j * CH + c8);
            }
#pragma unroll
            for (int i = 0; i < 4; ++i) {          // compute current batch
                float w = __expf(lrelu(aC[i] + adh) - mh);   // a=-1e30 -> w=0
                s += w;
                acc[0] = fmaf(w, bflo(hC[i].x), acc[0]);
                acc[1] = fmaf(w, bfhi(hC[i].x), acc[1]);
                acc[2] = fmaf(w, bflo(hC[i].y), acc[2]);
                acc[3] = fmaf(w, bfhi(hC[i].y), acc[3]);
                acc[4] = fmaf(w, bflo(hC[i].z), acc[4]);
                acc[5] = fmaf(w, bfhi(hC[i].z), acc[5]);
                acc[6] = fmaf(w, bflo(hC[i].w), acc[6]);
                acc[7] = fmaf(w, bfhi(hC[i].w), acc[7]);
            }
#pragma unroll
            for (int i = 0; i < 4; ++i) { aC[i] = aP[i]; hC[i] = hP[i]; }
            e = ebase;
            if (e >= end) break;
        }
    }
    if (g == 0) {   // self-loop message: w = exp(mh - mh) = 1 exactly
        s += 1.0f;
        uint4 hv = *(const uint4*)(h + (size_t)node * CH + c8);
        acc[0] += bflo(hv.x);
        acc[1] += bfhi(hv.x);
        acc[2] += bflo(hv.y);
        acc[3] += bfhi(hv.y);
        acc[4] += bflo(hv.z);
        acc[5] += bfhi(hv.z);
        acc[6] += bflo(hv.w);
        acc[7] += bfhi(hv.w);
    }
#pragma unroll
    for (int o = 16; o < 64; o <<= 1) {
        s += __shfl_xor(s, o, 64);
#pragma unroll
        for (int k = 0; k < 8; ++k) acc[k] += __shfl_xor(acc[k], o, 64);
    }
    if (g == 0) {
        const float inv = 1.f / (s + 1e-16f);
        float o0[8];
#pragma unroll
        for (int k = 0; k < 8; ++k) {
            float v = acc[k] * inv + bias[c8 + k];
            o0[k] = v > 0.f ? v : __expf(v) - 1.f;   // ELU alpha=1
        }
        float4 lo = make_float4(o0[0], o0[1], o0[2], o0[3]);
        float4 hi = make_float4(o0[4], o0[5], o0[6], o0[7]);
        *(float4*)(out + (size_t)node * CH + c8) = lo;
        *(float4*)(out + (size_t)node * CH + c8 + 4) = hi;
    }
}

extern "C" void kernel_launch(void* const* d_in, const int* in_sizes, int n_in,
                              void* d_out, int out_size, void* d_ws, size_t ws_size,
                              hipStream_t stream)
{
    const float* x       = (const float*)d_in[0];
    const int*   ei      = (const int*)d_in[1];
    const float* W       = (const float*)d_in[2];
    const float* att_src = (const float*)d_in[3];
    const float* att_dst = (const float*)d_in[4];
    const float* bias    = (const float*)d_in[5];
    float* out = (float*)d_out;
    const int N = in_sizes[0] / CH;
    const int E = in_sizes[1] / 2;
    const int NB = (N + NPB - 1) / NPB;   // coarse buckets (391 for N=50000)

    char* p = (char*)d_ws;
    auto alloc = [&](size_t bytes) { char* r = p; p += (bytes + 255) & ~(size_t)255; return r; };
    u16*   h    = (u16*)alloc((size_t)N * CH * 2);             // 12.8 MB
    float* asrc = (float*)alloc((size_t)N * NHEAD * 4);        // 0.8 MB
    float* adst = (float*)alloc((size_t)N * NHEAD * 4);        // 0.8 MB
    int*   gcur = (int*)alloc((size_t)NB * GPAD * 4);          // 25 KB
    u32*   rec  = (u32*)alloc((size_t)NB * BCAP * 4);          // 9.6 MB
    int*   csr  = (int*)alloc((size_t)NB * BCAP * 4 + 256);    // 9.6 MB + prefetch pad
    int*   begA = (int*)alloc((size_t)N * 4);
    int*   degA = (int*)alloc((size_t)N * 4);
    uint4* Wsw  = (uint4*)alloc((size_t)2048 * 16);            // 32 KB swizzled bf16 W

    const int gemmBlocks = (N + ROWS_PER_BLOCK - 1) / ROWS_PER_BLOCK;
    init_kernel<<<16, 256, 0, stream>>>(W, Wsw, gcur, NB * GPAD);
    gemmbin_kernel<<<BINA_BLOCKS + gemmBlocks, 256, 0, stream>>>(
        x, Wsw, att_src, att_dst, h, asrc, adst, N, ei, gcur, rec, E, NB);
    binB_kernel<<<NB, 256, 0, stream>>>(gcur, rec, csr, begA, degA, N);
    agg_kernel<<<(N + 3) / 4, 256, 0, stream>>>(h, asrc, adst, begA, degA, csr, bias, out, N);
}